// Round 1
// baseline (1490.804 us; speedup 1.0000x reference)
//
#include <hip/hip_runtime.h>

// Fused two-shot allreduce (sum over TP) + residual add + RMSNorm.
// x: [TP=8, T=4096, H=8192] f32; residual: [T,H] f32; norm_weight: [H] f32.
// Outputs (concatenated in d_out): output [T,H] f32, residual_out [T,H] f32.

constexpr int TP = 8;
constexpr int T = 4096;
constexpr int H = 8192;
constexpr float EPS = 1e-5f;
constexpr int THREADS = 256;          // 4 waves/block
constexpr int VEC = 4;                // float4
constexpr int CHUNKS = H / (THREADS * VEC);  // 8 chunks of 1024 floats

__global__ __launch_bounds__(THREADS)
void fused_allreduce_rmsnorm(const float* __restrict__ x,
                             const float* __restrict__ residual,
                             const float* __restrict__ w,
                             float* __restrict__ out,       // [T,H]
                             float* __restrict__ res_out) { // [T,H]
    const int row = blockIdx.x;
    const int tid = threadIdx.x;
    const size_t rowoff = (size_t)row * H;

    float4 acc[CHUNKS];
    float sumsq = 0.f;

    // Pass 1: sum the 8 TP partials + residual; keep residual_out in registers.
    // Coalesced: within a chunk, lane i touches base + i*16B.
#pragma unroll
    for (int c = 0; c < CHUNKS; ++c) {
        const size_t h = (size_t)c * (THREADS * VEC) + (size_t)tid * VEC;
        float4 a = *reinterpret_cast<const float4*>(residual + rowoff + h);
#pragma unroll
        for (int tp = 0; tp < TP; ++tp) {
            float4 v = *reinterpret_cast<const float4*>(
                x + (size_t)tp * T * H + rowoff + h);
            a.x += v.x; a.y += v.y; a.z += v.z; a.w += v.w;
        }
        acc[c] = a;
        // residual_out doesn't depend on the norm — store now so the writes
        // overlap with the remaining loads and the reduction.
        *reinterpret_cast<float4*>(res_out + rowoff + h) = a;
        sumsq += a.x * a.x + a.y * a.y + a.z * a.z + a.w * a.w;
    }

    // Block reduction of sum of squares (wave64 shuffle, then LDS across 4 waves).
#pragma unroll
    for (int off = 32; off > 0; off >>= 1)
        sumsq += __shfl_down(sumsq, off, 64);

    __shared__ float wave_sum[THREADS / 64];
    const int wid = tid >> 6;
    const int lane = tid & 63;
    if (lane == 0) wave_sum[wid] = sumsq;
    __syncthreads();
    const float total = wave_sum[0] + wave_sum[1] + wave_sum[2] + wave_sum[3];
    const float scale = rsqrtf(total * (1.0f / H) + EPS);

    // Pass 2: normalize from registers (no re-read of residual_out).
#pragma unroll
    for (int c = 0; c < CHUNKS; ++c) {
        const size_t h = (size_t)c * (THREADS * VEC) + (size_t)tid * VEC;
        const float4 a = acc[c];
        const float4 wv = *reinterpret_cast<const float4*>(w + h); // L2-hot, 32KB total
        float4 o;
        o.x = a.x * scale * wv.x;
        o.y = a.y * scale * wv.y;
        o.z = a.z * scale * wv.z;
        o.w = a.w * scale * wv.w;
        *reinterpret_cast<float4*>(out + rowoff + h) = o;
    }
}

extern "C" void kernel_launch(void* const* d_in, const int* in_sizes, int n_in,
                              void* d_out, int out_size, void* d_ws, size_t ws_size,
                              hipStream_t stream) {
    const float* x        = (const float*)d_in[0]; // [TP,T,H]
    const float* residual = (const float*)d_in[1]; // [T,H]
    const float* w        = (const float*)d_in[2]; // [H]
    float* out     = (float*)d_out;                // output [T,H]
    float* res_out = (float*)d_out + (size_t)T * H; // residual_out [T,H]

    fused_allreduce_rmsnorm<<<T, THREADS, 0, stream>>>(x, residual, w, out, res_out);
}